// Round 3
// baseline (213.424 us; speedup 1.0000x reference)
//
#include <hip/hip_runtime.h>
#include <hip/hip_bf16.h>

// Problem constants
#define DD   256
#define DD3  768
#define NB   128
#define NE   7      // 1 pos_u + 1 pos_v + 5 neg embeddings

// Workspace layout (float offsets)
#define OFF_TVT  0u          // tv transposed [256 i][128 b]
#define OFF_TVB  32768u      // tvB [128 b][256 j]
#define OFF_EMB  65536u      // emb [7 e][128 b][768 k] fp32
#define OFF_H3   753664u     // h3  [128 b][7 e][256 j]
#define OFF_G    983040u     // G = W4^T W4 [256][256]
#define OFF_GV   1048576u    // g = W4^T b4 [256]
#define OFF_SC   1048832u    // tvf (bf16 frags) aliased with scoreb/negb (tvf dead by k_score)

typedef __attribute__((ext_vector_type(8))) short bf16x8;
typedef __attribute__((ext_vector_type(4))) float f32x4;

__device__ __forceinline__ unsigned bf16rne(float f) {
  unsigned u = __float_as_uint(f);
  return (u + 0x7fffu + ((u >> 16) & 1u)) >> 16;   // round-to-nearest-even
}

__device__ __forceinline__ void gld16(const float* g, float* l) {
  __builtin_amdgcn_global_load_lds(
      (const __attribute__((address_space(1))) unsigned int*)g,
      (__attribute__((address_space(3))) unsigned int*)l, 16, 0, 0);
}

// ---------------------------------------------------------------------------
__global__ void k_setup(const float* __restrict__ timev,
                        const float* __restrict__ m1,
                        const float* __restrict__ b1,
                        const float* __restrict__ W2,
                        const float* __restrict__ b2,
                        const float* __restrict__ Bm,
                        float* __restrict__ tv_t,
                        float* __restrict__ tvB) {
  const int b = blockIdx.x, i = threadIdx.x;
  __shared__ float h1[DD];
  __shared__ float tvs[DD];
  const float t = timev[b] * (1.0f / 20.0f);
  h1[i] = tanhf(fmaf(t, m1[i], b1[i]));
  __syncthreads();
  float acc = b2[i];
  const float* w2r = W2 + i * DD;
#pragma unroll 8
  for (int jj = 0; jj < DD; ++jj) acc = fmaf(h1[jj], w2r[jj], acc);
  const float tvi = tanhf(acc);
  tvs[i] = tvi;
  tv_t[i * NB + b] = tvi;
  __syncthreads();
  float a2 = 0.f;
#pragma unroll 8
  for (int ii = 0; ii < DD; ++ii) a2 = fmaf(tvs[ii], Bm[ii * DD + i], a2);
  tvB[b * DD + i] = a2;
}

// ---------------------------------------------------------------------------
// Pack tv into bf16 MFMA B-fragments: frag f = bf*8+it (bf = b-frag 0..7)
__global__ void k_pack(const float* __restrict__ tv_t, short* __restrict__ tvf) {
  const int t = blockIdx.x * 256 + threadIdx.x;   // 4096 threads
  const int f = t >> 6, l = t & 63;
  const int b = (f >> 3) * 16 + (l & 15);
  const int i0 = (f & 7) * 32 + ((l >> 4) & 3) * 8;
  bf16x8 v;
#pragma unroll
  for (int jj = 0; jj < 8; ++jj)
    v[jj] = (short)bf16rne(tv_t[(i0 + jj) * NB + b]);
  *(bf16x8*)(tvf + (long)t * 8) = v;
}

// ---------------------------------------------------------------------------
__global__ void k_gather(const int* __restrict__ pos_u,
                         const int* __restrict__ pos_v,
                         const int* __restrict__ neg_v,
                         const float* __restrict__ U,
                         const float* __restrict__ V,
                         float* __restrict__ emb) {
  const int be = blockIdx.x;
  const int b = be / NE, e = be % NE;
  const float* src;
  if (e == 0)      src = U + (long)pos_u[b] * DD3;
  else if (e == 1) src = V + (long)pos_v[b] * DD3;
  else             src = V + (long)neg_v[b * 5 + (e - 2)] * DD3;
  const float4 v = ((const float4*)src)[threadIdx.x];
  ((float4*)(emb + ((long)e * NB + b) * DD3))[threadIdx.x] = v;
}

// ---------------------------------------------------------------------------
__global__ __launch_bounds__(1024) void k_gram(const float* __restrict__ W4,
                                               const float* __restrict__ b4,
                                               float* __restrict__ G,
                                               float* __restrict__ gv) {
  const int p = blockIdx.x, t = threadIdx.x;
  const int q = t & 255, nq = t >> 8;
  __shared__ float colp[DD3];
  __shared__ float red[4][257];
  __shared__ float gred[4];
  for (int n = t; n < DD3; n += 1024) colp[n] = W4[n * DD + p];
  __syncthreads();
  float acc = 0.f;
  const int n0 = nq * 192;
#pragma unroll 8
  for (int n = n0; n < n0 + 192; ++n) acc = fmaf(colp[n], W4[n * DD + q], acc);
  red[nq][q] = acc;
  float gp = 0.f;
  for (int n = n0; n < n0 + 192; ++n) gp = fmaf(b4[n], colp[n], gp);
  if (q == 0) gred[nq] = gp;
  __syncthreads();
  if (t < 256) G[p * DD + t] = red[0][t] + red[1][t] + red[2][t] + red[3][t];
  if (t == 0) gv[p] = gred[0] + gred[1] + gred[2] + gred[3];
}

// ---------------------------------------------------------------------------
// Main kernel: grid 512 = (j 0..255) x (bh 0..1), pairs mapped to the SAME XCD
// (xcd = bid&7 round-robin assumption) so they share T[:,j,:] in L2.
// Per block: 8 waves = 4 bq (16 b) x 2 mh (64 k). MFMA D[m=k,n=b] over i.
// T staged fp32 via global_load_lds: 48 stages of [32 i][128 k] = 16 KB,
// 4 buffers (64 KB), prefetch depth 3, counted vmcnt(6), raw s_barrier.
// XOR-swizzle k ^= ((i>>3)&3)<<4 on BOTH global source and LDS read.
__global__ __launch_bounds__(512) void k_main(const float* __restrict__ T,
                                              const short* __restrict__ tvf,
                                              const float* __restrict__ emb,
                                              const float* __restrict__ tvB,
                                              float* __restrict__ h3) {
  __shared__ float Ts[4][4096];      // 4 x 16 KB
  __shared__ float h3red[64][NE];
  const int bid = blockIdx.x;
  const int xcd = bid & 7, slot = bid >> 3;
  const int j = xcd * 32 + (slot >> 1);
  const int bh = slot & 1;

  const int t = threadIdx.x;
  const int l = t & 63;
  const int w = t >> 6;
  const int bq = w >> 1;             // 0..3 (16 b each)
  const int mh = w & 1;              // k-half of 128-k chunk
  const int l15 = l & 15;
  const int l4 = (l >> 4) & 3;
  const int lhi = l >> 5;
  const int kb = (l & 31) * 4;

  // Preload tv B-fragments for this wave's 16 b (bf = bh*4+bq)
  const int bf = bh * 4 + bq;
  bf16x8 tvfr[8];
#pragma unroll
  for (int it = 0; it < 8; ++it)
    tvfr[it] = *(const bf16x8*)(tvf + (((bf * 8) + it) * 64 + l) * 8);

  // Pre-swizzled per-lane global staging pointers
  const int i0 = 4 * w + lhi, i1 = i0 + 2;
  const float* gp0 = T + (long)i0 * 196608 + j * 768 + (kb ^ (((i0 >> 3) & 3) << 4));
  const float* gp1 = T + (long)i1 * 196608 + j * 768 + (kb ^ (((i1 >> 3) & 3) << 4));

  auto stage = [&](int sid) {
    const int itp = sid & 7, kcp = sid >> 3, bufp = sid & 3;
    const long o = (long)itp * 6291456 + kcp * 128;
    gld16(gp0 + o, &Ts[bufp][(w * 2 + 0) * 256]);
    gld16(gp1 + o, &Ts[bufp][(w * 2 + 1) * 256]);
  };

  float h3p[NE];
#pragma unroll
  for (int e = 0; e < NE; ++e) h3p[e] = 0.f;

  const int kcol0 = mh * 64;

  auto compute = [&](int buf, int it, f32x4 (&acc)[4]) {
    const float* tsb = &Ts[buf][0];
    __builtin_amdgcn_s_setprio(1);
#pragma unroll
    for (int mf = 0; mf < 4; ++mf) {
      const int kx = (kcol0 + mf * 16 + l15) ^ (l4 << 4);
      bf16x8 af;
#pragma unroll
      for (int jj = 0; jj < 8; ++jj)
        af[jj] = (short)bf16rne(tsb[(l4 * 8 + jj) * 128 + kx]);
      acc[mf] = __builtin_amdgcn_mfma_f32_16x16x32_bf16(af, tvfr[it], acc[mf], 0, 0, 0);
    }
    __builtin_amdgcn_s_setprio(0);
  };

  auto epilogue = [&](int kc, f32x4 (&acc)[4]) {
    const int b = bh * 64 + bq * 16 + l15;
#pragma unroll
    for (int mf = 0; mf < 4; ++mf) {
      const long ko = (long)kc * 128 + mh * 64 + mf * 16 + l4 * 4;
#pragma unroll
      for (int e = 0; e < NE; ++e) {
        const f32x4 em = *(const f32x4*)(emb + ((long)e * NB + b) * 768 + ko);
        float s = h3p[e];
        s = fmaf(acc[mf][0], em[0], s);
        s = fmaf(acc[mf][1], em[1], s);
        s = fmaf(acc[mf][2], em[2], s);
        s = fmaf(acc[mf][3], em[3], s);
        h3p[e] = s;
      }
    }
  };

  // Prologue: 3 stages in flight
  stage(0); stage(1); stage(2);

#pragma unroll 1
  for (int kc = 0; kc < 5; ++kc) {
    f32x4 acc[4];
#pragma unroll
    for (int mf = 0; mf < 4; ++mf) acc[mf] = {0.f, 0.f, 0.f, 0.f};
#pragma unroll
    for (int it = 0; it < 8; ++it) {
      const int sid = kc * 8 + it;
      stage(sid + 3);
      asm volatile("s_waitcnt vmcnt(6)" ::: "memory");
      __builtin_amdgcn_s_barrier();
      asm volatile("" ::: "memory");
      compute(sid & 3, it, acc);
      asm volatile("" ::: "memory");
      __builtin_amdgcn_s_barrier();
    }
    epilogue(kc, acc);
  }
  // Peeled last kc = 5 (compile-time vmcnt tail)
  {
    f32x4 acc[4];
#pragma unroll
    for (int mf = 0; mf < 4; ++mf) acc[mf] = {0.f, 0.f, 0.f, 0.f};
#pragma unroll
    for (int it = 0; it < 8; ++it) {
      const int sid = 40 + it;
      if (it < 5) {
        stage(sid + 3);
        asm volatile("s_waitcnt vmcnt(6)" ::: "memory");
      } else if (it == 5) {
        asm volatile("s_waitcnt vmcnt(4)" ::: "memory");
      } else if (it == 6) {
        asm volatile("s_waitcnt vmcnt(2)" ::: "memory");
      } else {
        asm volatile("s_waitcnt vmcnt(0)" ::: "memory");
      }
      __builtin_amdgcn_s_barrier();
      asm volatile("" ::: "memory");
      compute(sid & 3, it, acc);
      asm volatile("" ::: "memory");
      __builtin_amdgcn_s_barrier();
    }
    epilogue(5, acc);
  }

  // Reduce over the 4 lane-quads (k rows), then across mh via LDS
  float hr[NE];
#pragma unroll
  for (int e = 0; e < NE; ++e) {
    float v = h3p[e];
    v += __shfl_xor(v, 16);
    v += __shfl_xor(v, 32);
    hr[e] = v;
  }
  __syncthreads();
  if (mh == 0 && l < 16) {
#pragma unroll
    for (int e = 0; e < NE; ++e) h3red[bq * 16 + l][e] = hr[e];
  }
  __syncthreads();
  if (mh == 1 && l < 16) {
    const int bl = bq * 16 + l;
    const int b = bh * 64 + bl;
    const float tb = tvB[b * DD + j];
#pragma unroll
    for (int e = 0; e < NE; ++e)
      h3[((long)b * NE + e) * DD + j] = h3red[bl][e] + hr[e] + tb;
  }
}

// ---------------------------------------------------------------------------
__global__ void k_score(const float* __restrict__ h3,
                        const float* __restrict__ G,
                        const float* __restrict__ gv,
                        const float* __restrict__ b4,
                        float* __restrict__ scoreb,
                        float* __restrict__ negb) {
  const int b = blockIdx.x, t = threadIdx.x;
  __shared__ float h3s[NE * DD];
  __shared__ float red[4][16];
  for (int idx = t; idx < NE * DD; idx += 256) h3s[idx] = h3[(long)b * NE * DD + idx];
  __syncthreads();
  float racc = 0.f;
#pragma unroll 8
  for (int jp = 0; jp < DD; ++jp) racc = fmaf(G[jp * DD + t], h3s[jp], racc);

  float loc[14];
#pragma unroll
  for (int e = 1; e < NE; ++e) loc[e - 1] = racc * h3s[e * DD + t];
  loc[6] = gv[t] * h3s[t];
#pragma unroll
  for (int e = 1; e < NE; ++e) loc[6 + e] = gv[t] * h3s[e * DD + t];
  loc[13] = b4[t] * b4[t] + b4[t + 256] * b4[t + 256] + b4[t + 512] * b4[t + 512];

  const int lane = t & 63, wid = t >> 6;
#pragma unroll
  for (int qd = 0; qd < 14; ++qd) {
    float v = loc[qd];
#pragma unroll
    for (int m = 1; m < 64; m <<= 1) v += __shfl_xor(v, m);
    if (lane == 0) red[wid][qd] = v;
  }
  __syncthreads();
  if (t == 0) {
    float r[14];
#pragma unroll
    for (int qd = 0; qd < 14; ++qd)
      r[qd] = red[0][qd] + red[1][qd] + red[2][qd] + red[3][qd];
    const float c = r[13], gu = r[6];
    auto logsig = [](float x) { return fminf(x, 0.f) - log1pf(expf(-fabsf(x))); };
    float dv = r[0] + gu + r[7] + c;
    dv = fminf(fmaxf(dv, -10.f), 10.f);
    const float sc = -logsig(dv);
    float ns = 0.f;
    for (int lx = 1; lx < 6; ++lx) {
      float dn = r[lx] + gu + r[7 + lx] + c;
      dn = fminf(fmaxf(dn, -10.f), 10.f);
      ns -= logsig(-dn);
    }
    scoreb[b] = sc;
    negb[b] = ns * 0.2f;
  }
}

// ---------------------------------------------------------------------------
__global__ void k_final(const float* __restrict__ scoreb,
                        const float* __restrict__ negb,
                        float* __restrict__ out) {
  const int t = threadIdx.x;
  float s = scoreb[t], n = negb[t];
#pragma unroll
  for (int m = 1; m < 64; m <<= 1) {
    s += __shfl_xor(s, m);
    n += __shfl_xor(n, m);
  }
  __shared__ float rs[2], rn[2];
  if ((t & 63) == 0) { rs[t >> 6] = s; rn[t >> 6] = n; }
  __syncthreads();
  if (t == 0) {
    const float S = (rs[0] + rs[1]) * (1.0f / 128.0f);
    const float N = (rn[0] + rn[1]) * (1.0f / 128.0f);
    out[0] = S + N;
    out[1] = S;
    out[2] = N;
  }
}

// ---------------------------------------------------------------------------
extern "C" void kernel_launch(void* const* d_in, const int* in_sizes, int n_in,
                              void* d_out, int out_size, void* d_ws, size_t ws_size,
                              hipStream_t stream) {
  const int*   pos_u = (const int*)d_in[0];
  const int*   pos_v = (const int*)d_in[1];
  const int*   neg_v = (const int*)d_in[2];
  const float* timev = (const float*)d_in[3];
  const float* m1    = (const float*)d_in[4];
  const float* b1    = (const float*)d_in[5];
  const float* W2    = (const float*)d_in[6];
  const float* b2    = (const float*)d_in[7];
  const float* W4    = (const float*)d_in[8];
  const float* b4    = (const float*)d_in[9];
  const float* U     = (const float*)d_in[10];
  const float* V     = (const float*)d_in[11];
  const float* T     = (const float*)d_in[12];
  const float* Bm    = (const float*)d_in[13];

  float* ws     = (float*)d_ws;
  float* tv_t   = ws + OFF_TVT;
  float* tvB    = ws + OFF_TVB;
  float* emb    = ws + OFF_EMB;
  float* h3     = ws + OFF_H3;
  float* G      = ws + OFF_G;
  float* gv     = ws + OFF_GV;
  short* tvf    = (short*)(ws + OFF_SC);
  float* scoreb = ws + OFF_SC;
  float* negb   = ws + OFF_SC + 128;
  float* out    = (float*)d_out;

  k_setup<<<128, 256, 0, stream>>>(timev, m1, b1, W2, b2, Bm, tv_t, tvB);
  k_pack<<<16, 256, 0, stream>>>(tv_t, tvf);
  k_gather<<<896, 192, 0, stream>>>(pos_u, pos_v, neg_v, U, V, emb);
  k_gram<<<256, 1024, 0, stream>>>(W4, b4, G, gv);
  k_main<<<512, 512, 0, stream>>>(T, tvf, emb, tvB, h3);
  k_score<<<128, 256, 0, stream>>>(h3, G, gv, b4, scoreb, negb);
  k_final<<<1, 128, 0, stream>>>(scoreb, negb, out);
}

// Round 4
// 205.500 us; speedup vs baseline: 1.0386x; 1.0386x over previous
//
#include <hip/hip_runtime.h>
#include <hip/hip_bf16.h>

// Problem constants
#define DD   256
#define DD3  768
#define NB   128
#define NE   7      // 1 pos_u + 1 pos_v + 5 neg embeddings

// Workspace layout (float offsets)
#define OFF_TVT  0u          // tv transposed [256 i][128 b]
#define OFF_TVB  32768u      // tvB [128 b][256 j]
#define OFF_EMB  65536u      // emb [7 e][128 b][768 k] fp32
#define OFF_H3   753664u     // h3  [128 b][7 e][256 j]  (atomic-accumulated, zeroed per call)
#define OFF_G    983040u     // G = W4^T W4 [256][256]
#define OFF_GV   1048576u    // g = W4^T b4 [256]
#define OFF_SC   1048832u    // tvf (bf16 frags) aliased with scoreb/negb (tvf dead by k_score)

typedef __attribute__((ext_vector_type(8))) short bf16x8;
typedef __attribute__((ext_vector_type(4))) float f32x4;

__device__ __forceinline__ unsigned bf16rne(float f) {
  unsigned u = __float_as_uint(f);
  return (u + 0x7fffu + ((u >> 16) & 1u)) >> 16;   // round-to-nearest-even
}

__device__ __forceinline__ void gld16(const float* g, float* l) {
  __builtin_amdgcn_global_load_lds(
      (const __attribute__((address_space(1))) unsigned int*)g,
      (__attribute__((address_space(3))) unsigned int*)l, 16, 0, 0);
}

// ---------------------------------------------------------------------------
__global__ void k_setup(const float* __restrict__ timev,
                        const float* __restrict__ m1,
                        const float* __restrict__ b1,
                        const float* __restrict__ W2,
                        const float* __restrict__ b2,
                        const float* __restrict__ Bm,
                        float* __restrict__ tv_t,
                        float* __restrict__ tvB) {
  const int b = blockIdx.x, i = threadIdx.x;
  __shared__ float h1[DD];
  __shared__ float tvs[DD];
  const float t = timev[b] * (1.0f / 20.0f);
  h1[i] = tanhf(fmaf(t, m1[i], b1[i]));
  __syncthreads();
  float acc = b2[i];
  const float* w2r = W2 + i * DD;
#pragma unroll 8
  for (int jj = 0; jj < DD; ++jj) acc = fmaf(h1[jj], w2r[jj], acc);
  const float tvi = tanhf(acc);
  tvs[i] = tvi;
  tv_t[i * NB + b] = tvi;
  __syncthreads();
  float a2 = 0.f;
#pragma unroll 8
  for (int ii = 0; ii < DD; ++ii) a2 = fmaf(tvs[ii], Bm[ii * DD + i], a2);
  tvB[b * DD + i] = a2;
}

// ---------------------------------------------------------------------------
// Pack tv into bf16 MFMA B-fragments: frag f = bf*8+it (bf = b-frag 0..7)
__global__ void k_pack(const float* __restrict__ tv_t, short* __restrict__ tvf) {
  const int t = blockIdx.x * 256 + threadIdx.x;   // 4096 threads
  const int f = t >> 6, l = t & 63;
  const int b = (f >> 3) * 16 + (l & 15);
  const int i0 = (f & 7) * 32 + ((l >> 4) & 3) * 8;
  bf16x8 v;
#pragma unroll
  for (int jj = 0; jj < 8; ++jj)
    v[jj] = (short)bf16rne(tv_t[(i0 + jj) * NB + b]);
  *(bf16x8*)(tvf + (long)t * 8) = v;
}

// ---------------------------------------------------------------------------
__global__ void k_gather(const int* __restrict__ pos_u,
                         const int* __restrict__ pos_v,
                         const int* __restrict__ neg_v,
                         const float* __restrict__ U,
                         const float* __restrict__ V,
                         float* __restrict__ emb) {
  const int be = blockIdx.x;
  const int b = be / NE, e = be % NE;
  const float* src;
  if (e == 0)      src = U + (long)pos_u[b] * DD3;
  else if (e == 1) src = V + (long)pos_v[b] * DD3;
  else             src = V + (long)neg_v[b * 5 + (e - 2)] * DD3;
  const float4 v = ((const float4*)src)[threadIdx.x];
  ((float4*)(emb + ((long)e * NB + b) * DD3))[threadIdx.x] = v;
}

// ---------------------------------------------------------------------------
__global__ __launch_bounds__(1024) void k_gram(const float* __restrict__ W4,
                                               const float* __restrict__ b4,
                                               float* __restrict__ G,
                                               float* __restrict__ gv) {
  const int p = blockIdx.x, t = threadIdx.x;
  const int q = t & 255, nq = t >> 8;
  __shared__ float colp[DD3];
  __shared__ float red[4][257];
  __shared__ float gred[4];
  for (int n = t; n < DD3; n += 1024) colp[n] = W4[n * DD + p];
  __syncthreads();
  float acc = 0.f;
  const int n0 = nq * 192;
#pragma unroll 8
  for (int n = n0; n < n0 + 192; ++n) acc = fmaf(colp[n], W4[n * DD + q], acc);
  red[nq][q] = acc;
  float gp = 0.f;
  for (int n = n0; n < n0 + 192; ++n) gp = fmaf(b4[n], colp[n], gp);
  if (q == 0) gred[nq] = gp;
  __syncthreads();
  if (t < 256) G[p * DD + t] = red[0][t] + red[1][t] + red[2][t] + red[3][t];
  if (t == 0) gv[p] = gred[0] + gred[1] + gred[2] + gred[3];
}

// ---------------------------------------------------------------------------
// Main kernel: grid 1536 = (kc 0..5) x (j 0..255); bid = kc*256 + j.
// Each block handles ONE 128-k chunk of T[:, j, :] (disjoint 128 KB of T).
// 8 waves = 4 bq (32 b) x 2 mh (64 k). MFMA D[m=k,n=b] = sum_i T[i,j,k]*tv[b,i].
// T staged fp32 via global_load_lds: 8 stages of [32 i][128 k] = 16 KB,
// 3 buffers (48 KB), prefetch depth 2, counted vmcnt(4), raw s_barrier.
// XOR-swizzle k ^= ((i>>3)&3)<<4 on BOTH global source and LDS read.
// h3 contribution accumulated via atomicAdd (h3 zeroed per call).
__global__ __launch_bounds__(512, 4) void k_main(const float* __restrict__ T,
                                                 const short* __restrict__ tvf,
                                                 const float* __restrict__ emb,
                                                 const float* __restrict__ tvB,
                                                 float* __restrict__ h3) {
  __shared__ float Ts[3][4096];      // 3 x 16 KB
  __shared__ float h3red[NB][NE];
  const int bid = blockIdx.x;
  const int j = bid & 255;
  const int kc = bid >> 8;           // 0..5

  const int t = threadIdx.x;
  const int l = t & 63;
  const int w = t >> 6;
  const int bq = w >> 1;             // 0..3 (32 b each, via 2 nf)
  const int mh = w & 1;              // k-half of the 128-k chunk
  const int l15 = l & 15;
  const int l4 = (l >> 4) & 3;
  const int lhi = l >> 5;
  const int kb = (l & 31) * 4;

  // Preload tv B-fragments [nf][it] (bf16, packed by k_pack)
  bf16x8 tvfr[2][8];
#pragma unroll
  for (int nf = 0; nf < 2; ++nf)
#pragma unroll
    for (int it = 0; it < 8; ++it)
      tvfr[nf][it] = *(const bf16x8*)(tvf + ((((bq * 2 + nf) * 8) + it) * 64 + l) * 8);

  // Pre-swizzled per-lane global staging pointers (include this block's kc*128)
  const int i0 = 4 * w + lhi, i1 = i0 + 2;
  const float* gp0 = T + (long)i0 * 196608 + j * 768 + kc * 128 + (kb ^ (((i0 >> 3) & 3) << 4));
  const float* gp1 = T + (long)i1 * 196608 + j * 768 + kc * 128 + (kb ^ (((i1 >> 3) & 3) << 4));

  auto stage = [&](int it) {
    const int buf = it % 3;
    const long o = (long)it * 6291456;   // i-block stride = 32*196608
    gld16(gp0 + o, &Ts[buf][(w * 2 + 0) * 256]);
    gld16(gp1 + o, &Ts[buf][(w * 2 + 1) * 256]);
  };

  const int kcol0 = mh * 64;

  f32x4 acc[4][2];
#pragma unroll
  for (int mf = 0; mf < 4; ++mf) {
    acc[mf][0] = {0.f, 0.f, 0.f, 0.f};
    acc[mf][1] = {0.f, 0.f, 0.f, 0.f};
  }

  // Prologue: 2 stages in flight
  stage(0); stage(1);

#pragma unroll
  for (int it = 0; it < 8; ++it) {
    if (it < 6) {
      stage(it + 2);
      asm volatile("s_waitcnt vmcnt(4)" ::: "memory");
    } else if (it == 6) {
      asm volatile("s_waitcnt vmcnt(2)" ::: "memory");
    } else {
      asm volatile("s_waitcnt vmcnt(0)" ::: "memory");
    }
    __builtin_amdgcn_s_barrier();
    asm volatile("" ::: "memory");
    const float* tsb = &Ts[it % 3][0];
    __builtin_amdgcn_s_setprio(1);
#pragma unroll
    for (int mf = 0; mf < 4; ++mf) {
      const int kx = (kcol0 + mf * 16 + l15) ^ (l4 << 4);
      bf16x8 af;
#pragma unroll
      for (int jj = 0; jj < 8; ++jj)
        af[jj] = (short)bf16rne(tsb[(l4 * 8 + jj) * 128 + kx]);
      acc[mf][0] = __builtin_amdgcn_mfma_f32_16x16x32_bf16(af, tvfr[0][it], acc[mf][0], 0, 0, 0);
      acc[mf][1] = __builtin_amdgcn_mfma_f32_16x16x32_bf16(af, tvfr[1][it], acc[mf][1], 0, 0, 0);
    }
    __builtin_amdgcn_s_setprio(0);
    asm volatile("" ::: "memory");
    __builtin_amdgcn_s_barrier();
    asm volatile("" ::: "memory");
  }

  // Epilogue: contract this 128-k chunk with embeddings
  float h3p[NE][2];
#pragma unroll
  for (int e = 0; e < NE; ++e) { h3p[e][0] = 0.f; h3p[e][1] = 0.f; }
#pragma unroll
  for (int nf = 0; nf < 2; ++nf) {
    const int b = bq * 32 + nf * 16 + l15;
#pragma unroll
    for (int mf = 0; mf < 4; ++mf) {
      const long ko = (long)kc * 128 + mh * 64 + mf * 16 + l4 * 4;
#pragma unroll
      for (int e = 0; e < NE; ++e) {
        const f32x4 em = *(const f32x4*)(emb + ((long)e * NB + b) * 768 + ko);
        float s = h3p[e][nf];
        s = fmaf(acc[mf][nf][0], em[0], s);
        s = fmaf(acc[mf][nf][1], em[1], s);
        s = fmaf(acc[mf][nf][2], em[2], s);
        s = fmaf(acc[mf][nf][3], em[3], s);
        h3p[e][nf] = s;
      }
    }
  }

  // Reduce partials over the 4 lane-quads (k rows), then across mh via LDS
  float hr[NE][2];
#pragma unroll
  for (int e = 0; e < NE; ++e)
#pragma unroll
    for (int nf = 0; nf < 2; ++nf) {
      float v = h3p[e][nf];
      v += __shfl_xor(v, 16);
      v += __shfl_xor(v, 32);
      hr[e][nf] = v;
    }
  __syncthreads();
  if (mh == 0 && l < 16) {
#pragma unroll
    for (int e = 0; e < NE; ++e) {
      h3red[bq * 32 + l][e]      = hr[e][0];
      h3red[bq * 32 + 16 + l][e] = hr[e][1];
    }
  }
  __syncthreads();
  if (mh == 1 && l < 16) {
#pragma unroll
    for (int nf = 0; nf < 2; ++nf) {
      const int b = bq * 32 + nf * 16 + l;
      const float tb = (kc == 0) ? tvB[b * DD + j] : 0.f;
#pragma unroll
      for (int e = 0; e < NE; ++e)
        atomicAdd(&h3[((long)b * NE + e) * DD + j], h3red[b][e] + hr[e][nf] + tb);
    }
  }
}

// ---------------------------------------------------------------------------
__global__ void k_score(const float* __restrict__ h3,
                        const float* __restrict__ G,
                        const float* __restrict__ gv,
                        const float* __restrict__ b4,
                        float* __restrict__ scoreb,
                        float* __restrict__ negb) {
  const int b = blockIdx.x, t = threadIdx.x;
  __shared__ float h3s[NE * DD];
  __shared__ float red[4][16];
  for (int idx = t; idx < NE * DD; idx += 256) h3s[idx] = h3[(long)b * NE * DD + idx];
  __syncthreads();
  float racc = 0.f;
#pragma unroll 8
  for (int jp = 0; jp < DD; ++jp) racc = fmaf(G[jp * DD + t], h3s[jp], racc);

  float loc[14];
#pragma unroll
  for (int e = 1; e < NE; ++e) loc[e - 1] = racc * h3s[e * DD + t];
  loc[6] = gv[t] * h3s[t];
#pragma unroll
  for (int e = 1; e < NE; ++e) loc[6 + e] = gv[t] * h3s[e * DD + t];
  loc[13] = b4[t] * b4[t] + b4[t + 256] * b4[t + 256] + b4[t + 512] * b4[t + 512];

  const int lane = t & 63, wid = t >> 6;
#pragma unroll
  for (int qd = 0; qd < 14; ++qd) {
    float v = loc[qd];
#pragma unroll
    for (int m = 1; m < 64; m <<= 1) v += __shfl_xor(v, m);
    if (lane == 0) red[wid][qd] = v;
  }
  __syncthreads();
  if (t == 0) {
    float r[14];
#pragma unroll
    for (int qd = 0; qd < 14; ++qd)
      r[qd] = red[0][qd] + red[1][qd] + red[2][qd] + red[3][qd];
    const float c = r[13], gu = r[6];
    auto logsig = [](float x) { return fminf(x, 0.f) - log1pf(expf(-fabsf(x))); };
    float dv = r[0] + gu + r[7] + c;
    dv = fminf(fmaxf(dv, -10.f), 10.f);
    const float sc = -logsig(dv);
    float ns = 0.f;
    for (int lx = 1; lx < 6; ++lx) {
      float dn = r[lx] + gu + r[7 + lx] + c;
      dn = fminf(fmaxf(dn, -10.f), 10.f);
      ns -= logsig(-dn);
    }
    scoreb[b] = sc;
    negb[b] = ns * 0.2f;
  }
}

// ---------------------------------------------------------------------------
__global__ void k_final(const float* __restrict__ scoreb,
                        const float* __restrict__ negb,
                        float* __restrict__ out) {
  const int t = threadIdx.x;
  float s = scoreb[t], n = negb[t];
#pragma unroll
  for (int m = 1; m < 64; m <<= 1) {
    s += __shfl_xor(s, m);
    n += __shfl_xor(n, m);
  }
  __shared__ float rs[2], rn[2];
  if ((t & 63) == 0) { rs[t >> 6] = s; rn[t >> 6] = n; }
  __syncthreads();
  if (t == 0) {
    const float S = (rs[0] + rs[1]) * (1.0f / 128.0f);
    const float N = (rn[0] + rn[1]) * (1.0f / 128.0f);
    out[0] = S + N;
    out[1] = S;
    out[2] = N;
  }
}

// ---------------------------------------------------------------------------
extern "C" void kernel_launch(void* const* d_in, const int* in_sizes, int n_in,
                              void* d_out, int out_size, void* d_ws, size_t ws_size,
                              hipStream_t stream) {
  const int*   pos_u = (const int*)d_in[0];
  const int*   pos_v = (const int*)d_in[1];
  const int*   neg_v = (const int*)d_in[2];
  const float* timev = (const float*)d_in[3];
  const float* m1    = (const float*)d_in[4];
  const float* b1    = (const float*)d_in[5];
  const float* W2    = (const float*)d_in[6];
  const float* b2    = (const float*)d_in[7];
  const float* W4    = (const float*)d_in[8];
  const float* b4    = (const float*)d_in[9];
  const float* U     = (const float*)d_in[10];
  const float* V     = (const float*)d_in[11];
  const float* T     = (const float*)d_in[12];
  const float* Bm    = (const float*)d_in[13];

  float* ws     = (float*)d_ws;
  float* tv_t   = ws + OFF_TVT;
  float* tvB    = ws + OFF_TVB;
  float* emb    = ws + OFF_EMB;
  float* h3     = ws + OFF_H3;
  float* G      = ws + OFF_G;
  float* gv     = ws + OFF_GV;
  short* tvf    = (short*)(ws + OFF_SC);
  float* scoreb = ws + OFF_SC;
  float* negb   = ws + OFF_SC + 128;
  float* out    = (float*)d_out;

  hipMemsetAsync(h3, 0, (size_t)NB * NE * DD * sizeof(float), stream);
  k_setup<<<128, 256, 0, stream>>>(timev, m1, b1, W2, b2, Bm, tv_t, tvB);
  k_pack<<<16, 256, 0, stream>>>(tv_t, tvf);
  k_gather<<<896, 192, 0, stream>>>(pos_u, pos_v, neg_v, U, V, emb);
  k_gram<<<256, 1024, 0, stream>>>(W4, b4, G, gv);
  k_main<<<1536, 512, 0, stream>>>(T, tvf, emb, tvB, h3);
  k_score<<<128, 256, 0, stream>>>(h3, G, gv, b4, scoreb, negb);
  k_final<<<1, 128, 0, stream>>>(scoreb, negb, out);
}